// Round 1
// baseline (1165.839 us; speedup 1.0000x reference)
//
#include <hip/hip_runtime.h>
#include <math.h>
#include <stdint.h>

#define B_ 32
#define KV_LEN 4096
#define HID 4096
#define NH 32
#define NKV 8
#define HD 128
#define GQ 4                       // NH / NKV
#define EPS 1e-6f
#define THETA 1000000.0f
#define SCALE 0.08838834764831845f // 128^-0.5
#define QKV_ROWS ((NH + 2 * NKV) * HD)  // 6144
#define SPLITS 8
#define SCHUNK (KV_LEN / SPLITS)   // 512

// ---------------------------------------------------------------------------
// GEMM: out[b][j] = sum_k A[b][k] * Wt[j][k]   (A: [32][K], Wt: [rows][K])
// Block: 256 thr = 4 waves. Each block does 8 j-rows x 32 batches.
// wave w: j-quad = (w&1)*4, b-half = (w>>1)*16. Lanes split k (4 floats each).
// K staged in LDS in 256-col chunks (hidden is reused by every j row).
// ---------------------------------------------------------------------------
__global__ __launch_bounds__(256, 2)
void gemm_bt(const float* __restrict__ A, const float* __restrict__ Wt,
             float* __restrict__ out, int K, int ld_out) {
    __shared__ float sh[32][256];
    const int tid  = threadIdx.x;
    const int wave = tid >> 6;
    const int lane = tid & 63;
    const int jg   = (wave & 1) * 4;
    const int bg   = (wave >> 1) * 16;
    const int j0   = blockIdx.x * 8;

    float acc[4][16];
#pragma unroll
    for (int j = 0; j < 4; ++j)
#pragma unroll
        for (int b = 0; b < 16; ++b) acc[j][b] = 0.0f;

    for (int kc = 0; kc < K; kc += 256) {
        // stage A[32][kc:kc+256] -> LDS (coalesced float4)
#pragma unroll
        for (int i = 0; i < 8; ++i) {
            int f   = tid + i * 256;          // float4 index, 0..2047
            int row = f >> 6;                 // 64 float4 per row
            int c4  = f & 63;
            *reinterpret_cast<float4*>(&sh[row][c4 * 4]) =
                *reinterpret_cast<const float4*>(&A[(size_t)row * K + kc + c4 * 4]);
        }
        __syncthreads();

        float4 w4[4];
#pragma unroll
        for (int j = 0; j < 4; ++j)
            w4[j] = *reinterpret_cast<const float4*>(
                &Wt[(size_t)(j0 + jg + j) * K + kc + lane * 4]);

#pragma unroll
        for (int b = 0; b < 16; ++b) {
            float4 h4 = *reinterpret_cast<const float4*>(&sh[bg + b][lane * 4]);
#pragma unroll
            for (int j = 0; j < 4; ++j)
                acc[j][b] += w4[j].x * h4.x + w4[j].y * h4.y +
                             w4[j].z * h4.z + w4[j].w * h4.w;
        }
        __syncthreads();
    }

    // reduce k-partials across the 64 lanes; lane (j*16+b) writes output
#pragma unroll
    for (int j = 0; j < 4; ++j) {
#pragma unroll
        for (int b = 0; b < 16; ++b) {
            float v = acc[j][b];
#pragma unroll
            for (int m = 1; m < 64; m <<= 1) v += __shfl_xor(v, m);
            if (lane == j * 16 + b)
                out[(size_t)(bg + b) * ld_out + j0 + jg + j] = v;
        }
    }
}

// ---------------------------------------------------------------------------
// Post-QKV: per-head RMSNorm (q,k) + NeoX RoPE (q,k) + scatter k,v into cache.
// grid: (48 heads, 32 batch), 64 threads (thread i owns elems i and i+64).
// ---------------------------------------------------------------------------
__global__ __launch_bounds__(64)
void qkv_post(const float* __restrict__ qkv, const int* __restrict__ pos_ids,
              const int* __restrict__ out_loc, const float* __restrict__ qw,
              const float* __restrict__ kw, float* __restrict__ qbuf,
              float* __restrict__ kbuf, float* __restrict__ vbuf) {
    const int head = blockIdx.x;   // 0..31 q, 32..39 k, 40..47 v
    const int b    = blockIdx.y;
    const int i    = threadIdx.x;  // 0..63
    const float* row = qkv + (size_t)b * QKV_ROWS + head * HD;
    float x1 = row[i], x2 = row[i + 64];

    if (head >= NH + NKV) {  // v head: raw scatter
        int kh  = head - NH - NKV;
        int loc = out_loc[b];
        float* dst = vbuf + (((size_t)b * KV_LEN + loc) * NKV + kh) * HD;
        dst[i] = x1;
        dst[i + 64] = x2;
        return;
    }

    // RMSNorm over the 128-elem head
    float ss = x1 * x1 + x2 * x2;
#pragma unroll
    for (int m = 1; m < 64; m <<= 1) ss += __shfl_xor(ss, m);
    float r = rsqrtf(ss * (1.0f / 128.0f) + EPS);
    const float* w = (head < NH) ? qw : kw;
    float y1 = x1 * r * w[i];
    float y2 = x2 * r * w[i + 64];

    // NeoX RoPE: pair (i, i+64), angle = pos * THETA^(-i/64)
    float pos = (float)pos_ids[b];
    float inv_freq = expf(-(logf(THETA) / 64.0f) * (float)i);
    float ang = pos * inv_freq;
    float c = cosf(ang), s = sinf(ang);
    float o1 = y1 * c - y2 * s;
    float o2 = y2 * c + y1 * s;

    if (head < NH) {
        float* dst = qbuf + ((size_t)b * NH + head) * HD;
        dst[i] = o1;
        dst[i + 64] = o2;
    } else {
        int kh  = head - NH;
        int loc = out_loc[b];
        float* dst = kbuf + (((size_t)b * KV_LEN + loc) * NKV + kh) * HD;
        dst[i] = o1;
        dst[i + 64] = o2;
    }
}

// ---------------------------------------------------------------------------
// Flash-decode attention, split-KV. grid (8 splits, 8 kv-heads, 32 batch).
// 256 thr = 16 groups of 16 lanes; group owns one s-row per iteration
// (lane i reads k/v[4i:4i+4) and [64+4i:68+4i) -> contiguous 512 B per row).
// Online softmax for the 4 GQA q-heads; group partials merged via LDS.
// ---------------------------------------------------------------------------
__global__ __launch_bounds__(256, 4)
void attn_decode(const float* __restrict__ qbuf, const float* __restrict__ kbuf,
                 const float* __restrict__ vbuf, float* __restrict__ part_o,
                 float* __restrict__ part_m, float* __restrict__ part_l) {
    const int split = blockIdx.x, h = blockIdx.y, b = blockIdx.z;
    const int tid = threadIdx.x;
    const int grp = tid >> 4;   // 0..15
    const int i   = tid & 15;   // lane within group

    float4 qa[GQ], qb[GQ];
#pragma unroll
    for (int g = 0; g < GQ; ++g) {
        const float* qp = qbuf + ((size_t)b * NH + h * GQ + g) * HD;
        qa[g] = *reinterpret_cast<const float4*>(qp + 4 * i);
        qb[g] = *reinterpret_cast<const float4*>(qp + 64 + 4 * i);
    }

    float m[GQ], l[GQ];
    float4 oa[GQ], ob[GQ];
#pragma unroll
    for (int g = 0; g < GQ; ++g) {
        m[g] = -1e30f;
        l[g] = 0.0f;
        oa[g] = make_float4(0.f, 0.f, 0.f, 0.f);
        ob[g] = make_float4(0.f, 0.f, 0.f, 0.f);
    }

    const int s0 = split * SCHUNK;
    for (int t = 0; t < SCHUNK / 16; ++t) {  // 32 iterations
        const int s = s0 + t * 16 + grp;
        const float* krow = kbuf + (((size_t)b * KV_LEN + s) * NKV + h) * HD;
        const float* vrow = vbuf + (((size_t)b * KV_LEN + s) * NKV + h) * HD;
        float4 ka = *reinterpret_cast<const float4*>(krow + 4 * i);
        float4 kb = *reinterpret_cast<const float4*>(krow + 64 + 4 * i);
        float4 va = *reinterpret_cast<const float4*>(vrow + 4 * i);
        float4 vb = *reinterpret_cast<const float4*>(vrow + 64 + 4 * i);

#pragma unroll
        for (int g = 0; g < GQ; ++g) {
            float d = ka.x * qa[g].x + ka.y * qa[g].y + ka.z * qa[g].z + ka.w * qa[g].w +
                      kb.x * qb[g].x + kb.y * qb[g].y + kb.z * qb[g].z + kb.w * qb[g].w;
            d += __shfl_xor(d, 1);
            d += __shfl_xor(d, 2);
            d += __shfl_xor(d, 4);
            d += __shfl_xor(d, 8);
            float sc = d * SCALE;
            float mn = fmaxf(m[g], sc);
            float p    = __expf(sc - mn);
            float corr = __expf(m[g] - mn);   // ==1 unless new max
            l[g] = l[g] * corr + p;
            oa[g].x = oa[g].x * corr + p * va.x;
            oa[g].y = oa[g].y * corr + p * va.y;
            oa[g].z = oa[g].z * corr + p * va.z;
            oa[g].w = oa[g].w * corr + p * va.w;
            ob[g].x = ob[g].x * corr + p * vb.x;
            ob[g].y = ob[g].y * corr + p * vb.y;
            ob[g].z = ob[g].z * corr + p * vb.z;
            ob[g].w = ob[g].w * corr + p * vb.w;
            m[g] = mn;
        }
    }

    // merge the 16 group partials
    __shared__ float smo[16][GQ][HD];  // 32 KB
    __shared__ float smm[16][GQ];
    __shared__ float sml[16][GQ];
#pragma unroll
    for (int g = 0; g < GQ; ++g) {
        if (i == 0) { smm[grp][g] = m[g]; sml[grp][g] = l[g]; }
        smo[grp][g][4 * i + 0] = oa[g].x;
        smo[grp][g][4 * i + 1] = oa[g].y;
        smo[grp][g][4 * i + 2] = oa[g].z;
        smo[grp][g][4 * i + 3] = oa[g].w;
        smo[grp][g][64 + 4 * i + 0] = ob[g].x;
        smo[grp][g][64 + 4 * i + 1] = ob[g].y;
        smo[grp][g][64 + 4 * i + 2] = ob[g].z;
        smo[grp][g][64 + 4 * i + 3] = ob[g].w;
    }
    __syncthreads();

    for (int idx = tid; idx < GQ * HD; idx += 256) {
        int g = idx >> 7, d = idx & 127;
        float mstar = -1e30f;
#pragma unroll
        for (int r = 0; r < 16; ++r) mstar = fmaxf(mstar, smm[r][g]);
        float L = 0.0f, o = 0.0f;
#pragma unroll
        for (int r = 0; r < 16; ++r) {
            float w = __expf(smm[r][g] - mstar);
            L += w * sml[r][g];
            o += w * smo[r][g][d];
        }
        size_t pbase = (((size_t)b * NKV + h) * SPLITS + split) * GQ + g;
        part_o[pbase * HD + d] = o;   // unnormalized
        if (d == 0) { part_m[pbase] = mstar; part_l[pbase] = L; }
    }
}

// ---------------------------------------------------------------------------
// Combine the 8 KV-split partials per (b, kv-head, g). grid (8, 32), 128 thr.
// ---------------------------------------------------------------------------
__global__ __launch_bounds__(128)
void attn_combine(const float* __restrict__ part_o, const float* __restrict__ part_m,
                  const float* __restrict__ part_l, float* __restrict__ attn_out) {
    const int h = blockIdx.x, b = blockIdx.y;
    const int d = threadIdx.x;
#pragma unroll
    for (int g = 0; g < GQ; ++g) {
        float mstar = -1e30f;
#pragma unroll
        for (int s = 0; s < SPLITS; ++s) {
            size_t p = (((size_t)b * NKV + h) * SPLITS + s) * GQ + g;
            mstar = fmaxf(mstar, part_m[p]);
        }
        float L = 0.0f, o = 0.0f;
#pragma unroll
        for (int s = 0; s < SPLITS; ++s) {
            size_t p = (((size_t)b * NKV + h) * SPLITS + s) * GQ + g;
            float w = __expf(part_m[p] - mstar);
            L += w * part_l[p];
            o += w * part_o[p * HD + d];
        }
        attn_out[(size_t)b * (NH * HD) + (h * GQ + g) * HD + d] = o / L;
    }
}

// ---------------------------------------------------------------------------
extern "C" void kernel_launch(void* const* d_in, const int* in_sizes, int n_in,
                              void* d_out, int out_size, void* d_ws, size_t ws_size,
                              hipStream_t stream) {
    const int*   pos    = (const int*)d_in[0];
    const float* hidden = (const float*)d_in[1];
    float*       kbuf   = (float*)d_in[2];
    float*       vbuf   = (float*)d_in[3];
    const int*   loc    = (const int*)d_in[4];
    const float* wqkv   = (const float*)d_in[5];
    const float* wo     = (const float*)d_in[6];
    const float* qnw    = (const float*)d_in[7];
    const float* knw    = (const float*)d_in[8];
    float*       out    = (float*)d_out;

    float* ws     = (float*)d_ws;
    float* qkv    = ws;                              // 32*6144   = 196608
    float* qbuf   = qkv + (size_t)B_ * QKV_ROWS;     // 32*32*128 = 131072
    float* part_o = qbuf + (size_t)B_ * NH * HD;     // 32*8*8*4*128 = 1048576
    float* part_m = part_o + (size_t)B_ * NKV * SPLITS * GQ * HD;  // 8192
    float* part_l = part_m + (size_t)B_ * NKV * SPLITS * GQ;       // 8192
    float* attn   = part_l + (size_t)B_ * NKV * SPLITS * GQ;       // 131072

    gemm_bt<<<QKV_ROWS / 8, 256, 0, stream>>>(hidden, wqkv, qkv, HID, QKV_ROWS);
    qkv_post<<<dim3(NH + 2 * NKV, B_), 64, 0, stream>>>(qkv, pos, loc, qnw, knw,
                                                        qbuf, kbuf, vbuf);
    attn_decode<<<dim3(SPLITS, NKV, B_), 256, 0, stream>>>(qbuf, kbuf, vbuf,
                                                           part_o, part_m, part_l);
    attn_combine<<<dim3(NKV, B_), 128, 0, stream>>>(part_o, part_m, part_l, attn);
    gemm_bt<<<HID / 8, 256, 0, stream>>>(attn, wo, out, HID, HID);
}

// Round 3
// 1149.821 us; speedup vs baseline: 1.0139x; 1.0139x over previous
//
#include <hip/hip_runtime.h>
#include <math.h>
#include <stdint.h>

#define B_ 32
#define KV_LEN 4096
#define HID 4096
#define NH 32
#define NKV 8
#define HD 128
#define GQ 4                       // NH / NKV
#define EPS 1e-6f
#define THETA 1000000.0f
#define SCALE 0.08838834764831845f // 128^-0.5
#define QKV_ROWS ((NH + 2 * NKV) * HD)  // 6144
#define SPLITS 8
#define SCHUNK (KV_LEN / SPLITS)   // 512
#define NT (SCHUNK / 16)           // 32 iterations

// ---------------------------------------------------------------------------
// GEMM: out[b][j] = sum_k A[b][k] * Wt[j][k]   (A: [32][K], Wt: [rows][K])
// 256 thr = 4 waves; block does 8 j-rows x 32 batches, k split across lanes.
// Double-buffered LDS staged via global_load_lds (async, width 16).
// Per wave-iter i the staged row is 4*i+wave (wave-uniform), lane-linear 16B.
// ---------------------------------------------------------------------------
__global__ __launch_bounds__(256, 2)
void gemm_bt(const float* __restrict__ A, const float* __restrict__ Wt,
             float* __restrict__ out, int K, int ld_out) {
    __shared__ __align__(16) float sh[2][32][256];   // 64 KB -> 2 blocks/CU
    const int tid  = threadIdx.x;
    const int wave = tid >> 6;
    const int lane = tid & 63;
    const int jg   = (wave & 1) * 4;
    const int bg   = (wave >> 1) * 16;
    const int j0   = blockIdx.x * 8;

    float acc[4][16];
#pragma unroll
    for (int j = 0; j < 4; ++j)
#pragma unroll
        for (int b = 0; b < 16; ++b) acc[j][b] = 0.0f;

    const int nk = K >> 8;

    // stage chunk 0 (async direct-to-LDS; dest = wave-uniform base + lane*16)
#pragma unroll
    for (int i = 0; i < 8; ++i) {
        const int row = 4 * i + wave;
        __builtin_amdgcn_global_load_lds(
            (const __attribute__((address_space(1))) void*)(A + (size_t)row * K + lane * 4),
            (__attribute__((address_space(3))) void*)&sh[0][row][0], 16, 0, 0);
    }
    __syncthreads();

    for (int c = 0; c < nk; ++c) {
        const int cur = c & 1;
        if (c + 1 < nk) {  // issue next chunk's staging before compute
            const int kcn = (c + 1) << 8;
#pragma unroll
            for (int i = 0; i < 8; ++i) {
                const int row = 4 * i + wave;
                __builtin_amdgcn_global_load_lds(
                    (const __attribute__((address_space(1))) void*)(A + (size_t)row * K + kcn + lane * 4),
                    (__attribute__((address_space(3))) void*)&sh[cur ^ 1][row][0], 16, 0, 0);
            }
        }
        const int kc = c << 8;
        float4 w4[4];
#pragma unroll
        for (int j = 0; j < 4; ++j)
            w4[j] = *reinterpret_cast<const float4*>(
                &Wt[(size_t)(j0 + jg + j) * K + kc + lane * 4]);

#pragma unroll
        for (int b = 0; b < 16; ++b) {
            float4 h4 = *reinterpret_cast<const float4*>(&sh[cur][bg + b][lane * 4]);
#pragma unroll
            for (int j = 0; j < 4; ++j)
                acc[j][b] += w4[j].x * h4.x + w4[j].y * h4.y +
                             w4[j].z * h4.z + w4[j].w * h4.w;
        }
        __syncthreads();  // drains vmcnt -> next buffer ready, LDS reads done
    }

    // reduce k-partials across 64 lanes; lane (j*16+b) keeps its value
    float myv = 0.0f;
#pragma unroll
    for (int j = 0; j < 4; ++j) {
#pragma unroll
        for (int b = 0; b < 16; ++b) {
            float v = acc[j][b];
#pragma unroll
            for (int m = 1; m < 64; m <<= 1) v += __shfl_xor(v, m);
            if (lane == j * 16 + b) myv = v;
        }
    }
    out[(size_t)(bg + (lane & 15)) * ld_out + j0 + jg + (lane >> 4)] = myv;
}

// ---------------------------------------------------------------------------
// Post-QKV: per-head RMSNorm (q,k) + NeoX RoPE (q,k). q scaled by SCALE.
// New-token k/v go to workspace (cache buffers are never written; attention
// substitutes them at s == out_loc). grid (48 heads, 32 batch), 64 thr.
// ---------------------------------------------------------------------------
__global__ __launch_bounds__(64)
void qkv_post(const float* __restrict__ qkv, const int* __restrict__ pos_ids,
              const float* __restrict__ qw, const float* __restrict__ kw,
              float* __restrict__ qbuf, float* __restrict__ knew,
              float* __restrict__ vnew) {
    const int head = blockIdx.x;   // 0..31 q, 32..39 k, 40..47 v
    const int b    = blockIdx.y;
    const int i    = threadIdx.x;  // 0..63
    const float* row = qkv + (size_t)b * QKV_ROWS + head * HD;
    float x1 = row[i], x2 = row[i + 64];

    if (head >= NH + NKV) {  // v head: raw copy to workspace
        float* dst = vnew + ((size_t)b * NKV + (head - NH - NKV)) * HD;
        dst[i] = x1;
        dst[i + 64] = x2;
        return;
    }

    float ss = x1 * x1 + x2 * x2;
#pragma unroll
    for (int m = 1; m < 64; m <<= 1) ss += __shfl_xor(ss, m);
    float r = rsqrtf(ss * (1.0f / 128.0f) + EPS);
    const float* w = (head < NH) ? qw : kw;
    float y1 = x1 * r * w[i];
    float y2 = x2 * r * w[i + 64];

    float pos = (float)pos_ids[b];
    float inv_freq = expf(-(logf(THETA) / 64.0f) * (float)i);
    float ang = pos * inv_freq;
    float c = cosf(ang), s = sinf(ang);
    float o1 = y1 * c - y2 * s;
    float o2 = y2 * c + y1 * s;

    if (head < NH) {
        float* dst = qbuf + ((size_t)b * NH + head) * HD;
        dst[i] = o1 * SCALE;          // fold attention scale into q
        dst[i + 64] = o2 * SCALE;
    } else {
        float* dst = knew + ((size_t)b * NKV + (head - NH)) * HD;
        dst[i] = o1;
        dst[i + 64] = o2;
    }
}

// ---------------------------------------------------------------------------
// Flash-decode attention, split-KV. grid (8 splits, 8 kv-heads, 32 batch).
// 256 thr = 16 groups x 16 lanes; group owns one s-row/iter (512 B reads).
// launch_bounds (256,3): VGPR cap ~170, live state ~130 -> no spill.
// Software-pipelined k/v prefetch; cross-group merge in registers
// (butterfly xor 16/32), LDS merge only across the 4 waves (8.3 KB).
// ---------------------------------------------------------------------------
__global__ __launch_bounds__(256, 3)
void attn_decode(const float* __restrict__ qbuf, const float* __restrict__ kbuf,
                 const float* __restrict__ vbuf, const float* __restrict__ knew,
                 const float* __restrict__ vnew, const int* __restrict__ out_loc,
                 float* __restrict__ part_o, float* __restrict__ part_m,
                 float* __restrict__ part_l) {
    const int split = blockIdx.x, h = blockIdx.y, b = blockIdx.z;
    const int tid  = threadIdx.x;
    const int wave = tid >> 6;
    const int grp  = tid >> 4;   // 0..15
    const int i    = tid & 15;
    const int loc  = out_loc[b];

    float4 qa[GQ], qb[GQ];
#pragma unroll
    for (int g = 0; g < GQ; ++g) {
        const float* qp = qbuf + ((size_t)b * NH + h * GQ + g) * HD;
        qa[g] = *reinterpret_cast<const float4*>(qp + 4 * i);
        qb[g] = *reinterpret_cast<const float4*>(qp + 64 + 4 * i);
    }

    float m[GQ], l[GQ];
    float4 oa[GQ], ob[GQ];
#pragma unroll
    for (int g = 0; g < GQ; ++g) {
        m[g] = -1e30f; l[g] = 0.0f;
        oa[g] = make_float4(0.f, 0.f, 0.f, 0.f);
        ob[g] = make_float4(0.f, 0.f, 0.f, 0.f);
    }

    const float* kn = knew + ((size_t)b * NKV + h) * HD;
    const float* vn = vnew + ((size_t)b * NKV + h) * HD;
    const int s0 = split * SCHUNK;

    // prologue: load row for t=0
    int s = s0 + grp;
    const float* kr = (s == loc) ? kn : kbuf + (((size_t)b * KV_LEN + s) * NKV + h) * HD;
    const float* vr = (s == loc) ? vn : vbuf + (((size_t)b * KV_LEN + s) * NKV + h) * HD;
    float4 ka = *reinterpret_cast<const float4*>(kr + 4 * i);
    float4 kb = *reinterpret_cast<const float4*>(kr + 64 + 4 * i);
    float4 va = *reinterpret_cast<const float4*>(vr + 4 * i);
    float4 vb = *reinterpret_cast<const float4*>(vr + 64 + 4 * i);

    for (int t = 0; t < NT; ++t) {
        // prefetch t+1 (clamped re-load of same row on the last iter)
        const int tn = (t + 1 < NT) ? t + 1 : t;
        const int sn = s0 + tn * 16 + grp;
        const float* krn = (sn == loc) ? kn : kbuf + (((size_t)b * KV_LEN + sn) * NKV + h) * HD;
        const float* vrn = (sn == loc) ? vn : vbuf + (((size_t)b * KV_LEN + sn) * NKV + h) * HD;
        float4 ka_n = *reinterpret_cast<const float4*>(krn + 4 * i);
        float4 kb_n = *reinterpret_cast<const float4*>(krn + 64 + 4 * i);
        float4 va_n = *reinterpret_cast<const float4*>(vrn + 4 * i);
        float4 vb_n = *reinterpret_cast<const float4*>(vrn + 64 + 4 * i);

#pragma unroll
        for (int g = 0; g < GQ; ++g) {
            float d = ka.x * qa[g].x + ka.y * qa[g].y + ka.z * qa[g].z + ka.w * qa[g].w +
                      kb.x * qb[g].x + kb.y * qb[g].y + kb.z * qb[g].z + kb.w * qb[g].w;
            d += __shfl_xor(d, 1);
            d += __shfl_xor(d, 2);
            d += __shfl_xor(d, 4);
            d += __shfl_xor(d, 8);
            float mn   = fmaxf(m[g], d);
            float p    = __expf(d - mn);
            float corr = __expf(m[g] - mn);
            l[g] = l[g] * corr + p;
            oa[g].x = fmaf(oa[g].x, corr, p * va.x);
            oa[g].y = fmaf(oa[g].y, corr, p * va.y);
            oa[g].z = fmaf(oa[g].z, corr, p * va.z);
            oa[g].w = fmaf(oa[g].w, corr, p * va.w);
            ob[g].x = fmaf(ob[g].x, corr, p * vb.x);
            ob[g].y = fmaf(ob[g].y, corr, p * vb.y);
            ob[g].z = fmaf(ob[g].z, corr, p * vb.z);
            ob[g].w = fmaf(ob[g].w, corr, p * vb.w);
            m[g] = mn;
        }
        ka = ka_n; kb = kb_n; va = va_n; vb = vb_n;
    }

    // merge the 4 groups within each wave in registers (lanes i,i+16,i+32,i+48
    // hold the same element slice -> butterfly over xor 16, 32)
#pragma unroll
    for (int off = 16; off <= 32; off <<= 1) {
#pragma unroll
        for (int g = 0; g < GQ; ++g) {
            float mo = __shfl_xor(m[g], off);
            float lo = __shfl_xor(l[g], off);
            float M  = fmaxf(m[g], mo);
            float cs = __expf(m[g] - M);
            float co = __expf(mo - M);
            l[g] = l[g] * cs + lo * co;
            float4 t;
            t.x = __shfl_xor(oa[g].x, off); t.y = __shfl_xor(oa[g].y, off);
            t.z = __shfl_xor(oa[g].z, off); t.w = __shfl_xor(oa[g].w, off);
            oa[g].x = oa[g].x * cs + t.x * co; oa[g].y = oa[g].y * cs + t.y * co;
            oa[g].z = oa[g].z * cs + t.z * co; oa[g].w = oa[g].w * cs + t.w * co;
            t.x = __shfl_xor(ob[g].x, off); t.y = __shfl_xor(ob[g].y, off);
            t.z = __shfl_xor(ob[g].z, off); t.w = __shfl_xor(ob[g].w, off);
            ob[g].x = ob[g].x * cs + t.x * co; ob[g].y = ob[g].y * cs + t.y * co;
            ob[g].z = ob[g].z * cs + t.z * co; ob[g].w = ob[g].w * cs + t.w * co;
            m[g] = M;
        }
    }

    // merge the 4 waves via small LDS (lanes 0..15 of each wave hold the data)
    __shared__ float smo[4][GQ][HD];   // 8 KB
    __shared__ float smm[4][GQ];
    __shared__ float sml[4][GQ];
    if ((tid & 63) < 16) {
#pragma unroll
        for (int g = 0; g < GQ; ++g) {
            if (i == 0) { smm[wave][g] = m[g]; sml[wave][g] = l[g]; }
            smo[wave][g][4 * i + 0] = oa[g].x;
            smo[wave][g][4 * i + 1] = oa[g].y;
            smo[wave][g][4 * i + 2] = oa[g].z;
            smo[wave][g][4 * i + 3] = oa[g].w;
            smo[wave][g][64 + 4 * i + 0] = ob[g].x;
            smo[wave][g][64 + 4 * i + 1] = ob[g].y;
            smo[wave][g][64 + 4 * i + 2] = ob[g].z;
            smo[wave][g][64 + 4 * i + 3] = ob[g].w;
        }
    }
    __syncthreads();

    for (int idx = tid; idx < GQ * HD; idx += 256) {
        int g = idx >> 7, d = idx & 127;
        float M = fmaxf(fmaxf(smm[0][g], smm[1][g]), fmaxf(smm[2][g], smm[3][g]));
        float L = 0.0f, o = 0.0f;
#pragma unroll
        for (int w = 0; w < 4; ++w) {
            float wt = __expf(smm[w][g] - M);
            L += wt * sml[w][g];
            o += wt * smo[w][g][d];
        }
        size_t pbase = (((size_t)b * NKV + h) * SPLITS + split) * GQ + g;
        part_o[pbase * HD + d] = o;   // unnormalized
        if (d == 0) { part_m[pbase] = M; part_l[pbase] = L; }
    }
}

// ---------------------------------------------------------------------------
// Combine the 8 KV-split partials per (b, kv-head, g). grid (8, 32), 128 thr.
// ---------------------------------------------------------------------------
__global__ __launch_bounds__(128)
void attn_combine(const float* __restrict__ part_o, const float* __restrict__ part_m,
                  const float* __restrict__ part_l, float* __restrict__ attn_out) {
    const int h = blockIdx.x, b = blockIdx.y;
    const int d = threadIdx.x;
#pragma unroll
    for (int g = 0; g < GQ; ++g) {
        float mstar = -1e30f;
#pragma unroll
        for (int s = 0; s < SPLITS; ++s) {
            size_t p = (((size_t)b * NKV + h) * SPLITS + s) * GQ + g;
            mstar = fmaxf(mstar, part_m[p]);
        }
        float L = 0.0f, o = 0.0f;
#pragma unroll
        for (int s = 0; s < SPLITS; ++s) {
            size_t p = (((size_t)b * NKV + h) * SPLITS + s) * GQ + g;
            float w = __expf(part_m[p] - mstar);
            L += w * part_l[p];
            o += w * part_o[p * HD + d];
        }
        attn_out[(size_t)b * (NH * HD) + (h * GQ + g) * HD + d] = o / L;
    }
}

// ---------------------------------------------------------------------------
extern "C" void kernel_launch(void* const* d_in, const int* in_sizes, int n_in,
                              void* d_out, int out_size, void* d_ws, size_t ws_size,
                              hipStream_t stream) {
    const int*   pos    = (const int*)d_in[0];
    const float* hidden = (const float*)d_in[1];
    const float* kbuf   = (const float*)d_in[2];
    const float* vbuf   = (const float*)d_in[3];
    const int*   loc    = (const int*)d_in[4];
    const float* wqkv   = (const float*)d_in[5];
    const float* wo     = (const float*)d_in[6];
    const float* qnw    = (const float*)d_in[7];
    const float* knw    = (const float*)d_in[8];
    float*       out    = (float*)d_out;

    float* ws     = (float*)d_ws;
    float* qkv    = ws;                               // 32*6144
    float* qbuf   = qkv + (size_t)B_ * QKV_ROWS;      // 32*32*128
    float* knew   = qbuf + (size_t)B_ * NH * HD;      // 32*8*128
    float* vnew   = knew + (size_t)B_ * NKV * HD;     // 32*8*128
    float* part_o = vnew + (size_t)B_ * NKV * HD;     // 32*8*8*4*128
    float* part_m = part_o + (size_t)B_ * NKV * SPLITS * GQ * HD;
    float* part_l = part_m + (size_t)B_ * NKV * SPLITS * GQ;
    float* attnb  = part_l + (size_t)B_ * NKV * SPLITS * GQ;   // 32*32*128

    gemm_bt<<<QKV_ROWS / 8, 256, 0, stream>>>(hidden, wqkv, qkv, HID, QKV_ROWS);
    qkv_post<<<dim3(NH + 2 * NKV, B_), 64, 0, stream>>>(qkv, pos, qnw, knw,
                                                        qbuf, knew, vnew);
    attn_decode<<<dim3(SPLITS, NKV, B_), 256, 0, stream>>>(qbuf, kbuf, vbuf,
                                                           knew, vnew, loc,
                                                           part_o, part_m, part_l);
    attn_combine<<<dim3(NKV, B_), 128, 0, stream>>>(part_o, part_m, part_l, attnb);
    gemm_bt<<<HID / 8, 256, 0, stream>>>(attnb, wo, out, HID, HID);
}